// Round 3
// baseline (576.297 us; speedup 1.0000x reference)
//
#include <hip/hip_runtime.h>

// Problem constants (from the reference): D=15, C=2^15, P=2^15-1, M=4
// K = M*D = 60 path steps per sample, IN_DIM=1024, BATCH=32.
#define K_PATH 60
#define IN_DIM 1024
#define BATCH  32

// One 64-lane wave computes one (sample, path-step) dot product:
//   row = comb_idx[target[b]*K + k]
//   out[b*K+k]            = dot(x[b,:], W[row,:]) + bias[row]
//   out[B*K + b*K+k]      = comb_labels[target[b]*K + k]
// Each lane reads 16 floats (4x float4) of x and W, coalesced; then a
// 6-step shuffle reduction across the 64-lane wave.
__global__ __launch_bounds__(256) void hse_sparse_dot_kernel(
    const float* __restrict__ x,
    const float* __restrict__ W,
    const float* __restrict__ bias,
    const int*   __restrict__ comb_idx,
    const float* __restrict__ comb_labels,
    const int*   __restrict__ target,
    float*       __restrict__ out)
{
    const int gtid = blockIdx.x * blockDim.x + threadIdx.x;
    const int wave = gtid >> 6;          // one wave per (b,k) task
    const int lane = threadIdx.x & 63;
    if (wave >= BATCH * K_PATH) return;

    const int b = wave / K_PATH;
    const int k = wave - b * K_PATH;
    const int t = target[b];
    const int row = comb_idx[t * K_PATH + k];

    const float4* __restrict__ xp = (const float4*)(x + (size_t)b * IN_DIM);
    const float4* __restrict__ wp = (const float4*)(W + (size_t)row * IN_DIM);

    float acc = 0.0f;
#pragma unroll
    for (int i = 0; i < 4; ++i) {
        const float4 xv = xp[lane + i * 64];   // 64 lanes * 4 iters * 4 floats = 1024
        const float4 wv = wp[lane + i * 64];
        acc = fmaf(xv.x, wv.x, acc);
        acc = fmaf(xv.y, wv.y, acc);
        acc = fmaf(xv.z, wv.z, acc);
        acc = fmaf(xv.w, wv.w, acc);
    }

    // 64-lane wave reduction
#pragma unroll
    for (int off = 32; off > 0; off >>= 1)
        acc += __shfl_down(acc, off, 64);

    if (lane == 0) {
        out[wave] = acc + bias[row];
        out[BATCH * K_PATH + wave] = comb_labels[t * K_PATH + k];
    }
}

extern "C" void kernel_launch(void* const* d_in, const int* in_sizes, int n_in,
                              void* d_out, int out_size, void* d_ws, size_t ws_size,
                              hipStream_t stream) {
    // setup_inputs() order: x, W, b, comb_idx, comb_labels, target
    const float* x           = (const float*)d_in[0];
    const float* W           = (const float*)d_in[1];
    const float* bias        = (const float*)d_in[2];
    const int*   comb_idx    = (const int*)d_in[3];
    const float* comb_labels = (const float*)d_in[4];
    const int*   target      = (const int*)d_in[5];
    float* out = (float*)d_out;

    const int tasks   = BATCH * K_PATH;       // 1920 wave-tasks
    const int threads = 256;                  // 4 waves per block
    const int blocks  = (tasks * 64 + threads - 1) / threads;  // 480

    hse_sparse_dot_kernel<<<blocks, threads, 0, stream>>>(
        x, W, bias, comb_idx, comb_labels, target, out);
}